// Round 1
// baseline (2187.832 us; speedup 1.0000x reference)
//
#include <hip/hip_runtime.h>
#include <stdint.h>

// Problem constants (fixed by the reference)
#define NB       32
#define NC       128
#define NHW      1024            // H*W = 32*32
#define NT       32768           // tokens = B*H*W
#define NE       16
#define NHID     512
#define NOISE_N  524288u         // T*E

// ---------------- Threefry-2x32, 20 rounds (JAX) ----------------
__device__ __forceinline__ uint32_t rotl32(uint32_t x, uint32_t d) {
    return (x << d) | (x >> (32u - d));
}

__device__ __forceinline__ void threefry2x32_20(uint32_t k0, uint32_t k1,
                                                uint32_t& x0, uint32_t& x1) {
    const uint32_t ks0 = k0, ks1 = k1, ks2 = k0 ^ k1 ^ 0x1BD11BDAu;
    x0 += ks0; x1 += ks1;
#define TFR(r) { x0 += x1; x1 = rotl32(x1, r); x1 ^= x0; }
    TFR(13u) TFR(15u) TFR(26u) TFR(6u)
    x0 += ks1; x1 += ks2 + 1u;
    TFR(17u) TFR(29u) TFR(16u) TFR(24u)
    x0 += ks2; x1 += ks0 + 2u;
    TFR(13u) TFR(15u) TFR(26u) TFR(6u)
    x0 += ks0; x1 += ks1 + 3u;
    TFR(17u) TFR(29u) TFR(16u) TFR(24u)
    x0 += ks1; x1 += ks2 + 4u;
    TFR(13u) TFR(15u) TFR(26u) TFR(6u)
    x0 += ks2; x1 += ks0 + 5u;
#undef TFR
}

// XLA ErfInv32 (Giles' single-precision polynomial, as in xla math.cc)
__device__ __forceinline__ float erfinv_xla_f32(float x) {
    float w = -log1pf(-x * x);
    float p;
    if (w < 5.0f) {
        w = w - 2.5f;
        p = 2.81022636e-08f;
        p = fmaf(p, w, 3.43273939e-07f);
        p = fmaf(p, w, -3.5233877e-06f);
        p = fmaf(p, w, -4.39150654e-06f);
        p = fmaf(p, w, 0.00021858087f);
        p = fmaf(p, w, -0.00125372503f);
        p = fmaf(p, w, -0.00417768164f);
        p = fmaf(p, w, 0.246640727f);
        p = fmaf(p, w, 1.50140941f);
    } else {
        w = sqrtf(w) - 3.0f;
        p = -0.000200214257f;
        p = fmaf(p, w, 0.000100950558f);
        p = fmaf(p, w, 0.00134934322f);
        p = fmaf(p, w, -0.00367342844f);
        p = fmaf(p, w, 0.00573950773f);
        p = fmaf(p, w, -0.0076224613f);
        p = fmaf(p, w, 0.00943887047f);
        p = fmaf(p, w, 1.00167406f);
        p = fmaf(p, w, 2.83297682f);
    }
    return p * x;
}

// jax.random.normal(key(42), (T,E), f32), element i (row-major),
// with jax_threefry_partitionable=True (modern default):
//   counter = (hi=0, lo=i); bits = r0 ^ r1.
// (Legacy fallback if this fails: x0=i (or i-N/2), x1=i+N/2; bits = r0 or r1.)
__device__ __forceinline__ float jax_noise_elem(uint32_t i) {
    uint32_t x0 = 0u, x1 = i;
    threefry2x32_20(0u, 42u, x0, x1);
    uint32_t bits = x0 ^ x1;
    float f = __uint_as_float(0x3f800000u | (bits >> 9)) - 1.0f;  // [0,1)
    const float lo = -0.99999994f;                                // nextafter(-1,0)
    float u = f * 2.0f + lo;                                      // (maxval-minval)==2.0f
    u = fmaxf(lo, u);
    return 1.41421354f * erfinv_xla_f32(u);                       // f32(sqrt(2))
}

// ---------------- Kernel A: gating + noise + top-2 ----------------
// 512 blocks x 256 threads; each block = 64 consecutive tokens of one batch b.
__global__ __launch_bounds__(256) void moe_gate_kernel(
    const float* __restrict__ x,
    const float* __restrict__ gate_w, const float* __restrict__ gate_b,
    const float* __restrict__ noise_w, const float* __restrict__ noise_b,
    float* __restrict__ gates_out,        // [T,16] region of d_out
    int*   __restrict__ top_idx,          // [T,2]
    float* __restrict__ top_prob,         // [T,2]
    float* __restrict__ xt_out,           // [T,128] contiguous tokens (ws)
    int store_xt)
{
    __shared__ float xs[128][65];     // [c][tok], padded
    __shared__ float gw[128 * 16];
    __shared__ float nw[128 * 16];
    __shared__ float lg[64][17];      // noisy logits, padded

    const int tid = threadIdx.x;
    const int blk = blockIdx.x;               // 0..511
    const int b   = blk >> 4;
    const int hw0 = (blk & 15) << 6;          // 64 tokens per block
    const int t0  = blk * 64;

    // coalesced load of x tile: x[(b*128+c)*1024 + hw0 + hwl]
    {
        const size_t xbase = (size_t)b * (NC * NHW) + hw0;
        #pragma unroll
        for (int i = 0; i < 32; ++i) {
            int lin = i * 256 + tid;
            int c = lin >> 6, hwl = lin & 63;
            xs[c][hwl] = x[xbase + (size_t)c * NHW + hwl];
        }
    }
    #pragma unroll
    for (int i = 0; i < 8; ++i) {
        gw[i * 256 + tid] = gate_w[i * 256 + tid];
        nw[i * 256 + tid] = noise_w[i * 256 + tid];
    }
    __syncthreads();

    // 64 tokens x 16 experts = 1024 (tok,e) pairs; 4 per thread
    #pragma unroll
    for (int i = 0; i < 4; ++i) {
        int p = i * 256 + tid;
        int tok = p >> 4, e = p & 15;
        float ag = 0.f, an = 0.f;
        for (int d = 0; d < 128; ++d) {
            float xv = xs[d][tok];
            ag = fmaf(xv, gw[d * 16 + e], ag);
            an = fmaf(xv, nw[d * 16 + e], an);
        }
        ag += gate_b[e];
        an += noise_b[e];
        // softplus = max(v,0) + log1p(exp(-|v|))  (jnp.logaddexp(v,0))
        float sd = fmaxf(an, 0.f) + log1pf(expf(-fabsf(an)));
        uint32_t gi = (uint32_t)(t0 + tok) * 16u + (uint32_t)e;
        float nz = jax_noise_elem(gi);
        lg[tok][e] = fmaf(nz, sd, ag);
    }
    __syncthreads();

    // top-2 (lax.top_k tie-break: lowest index) + softmax over the 2 values
    if (tid < 64) {
        const int tok = tid;
        const int t = t0 + tok;
        float v1 = -INFINITY; int e1 = 0;
        #pragma unroll
        for (int e = 0; e < 16; ++e) {
            float v = lg[tok][e];
            if (v > v1) { v1 = v; e1 = e; }
        }
        float v2 = -INFINITY; int e2 = 0;
        #pragma unroll
        for (int e = 0; e < 16; ++e) {
            if (e == e1) continue;
            float v = lg[tok][e];
            if (v > v2) { v2 = v; e2 = e; }
        }
        // softmax([v1,v2]) with max = v1 (v1 >= v2): exp(0)=1, q=exp(v2-v1)
        float q = expf(v2 - v1);
        float s = 1.0f + q;
        float p1 = 1.0f / s;
        float p2 = q / s;
        #pragma unroll
        for (int e = 0; e < 16; ++e)
            gates_out[(size_t)t * 16 + e] = (e == e1) ? p1 : ((e == e2) ? p2 : 0.f);
        top_idx[t * 2 + 0] = e1;  top_idx[t * 2 + 1] = e2;
        top_prob[t * 2 + 0] = p1; top_prob[t * 2 + 1] = p2;
    }

    // store contiguous xt for kernel B (coalesced)
    if (store_xt) {
        #pragma unroll
        for (int i = 0; i < 32; ++i) {
            int lin = i * 256 + tid;
            int tok = lin >> 7, c = lin & 127;
            xt_out[(size_t)(t0 + tok) * 128 + c] = xs[c][tok];
        }
    }
}

// ---------------- Kernel B: per-token 2-expert fused MLP ----------------
// 32768 blocks x 256 threads; fp32 vector math (round-1 correctness build).
__global__ __launch_bounds__(256) void moe_expert_kernel(
    const float* __restrict__ x, const float* __restrict__ xt_ws, int use_xt,
    const int* __restrict__ top_idx, const float* __restrict__ top_prob,
    const float* __restrict__ w1, const float* __restrict__ b1,
    const float* __restrict__ w2, const float* __restrict__ b2,
    float* __restrict__ out)
{
    __shared__ float xsB[128];
    __shared__ float hb[512];

    const int tid = threadIdx.x;
    const int t = blockIdx.x;
    const int b = t >> 10, hw = t & 1023;

    if (tid < 128) {
        xsB[tid] = use_xt ? xt_ws[(size_t)t * 128 + tid]
                          : x[((size_t)b * 128 + tid) * NHW + hw];
    }
    __syncthreads();

    float oacc = 0.f;
    #pragma unroll
    for (int k = 0; k < 2; ++k) {
        const int e = top_idx[t * 2 + k];
        const float pw = top_prob[t * 2 + k];
        const float* W1 = w1 + (size_t)e * (128 * 512);
        float a0 = 0.f, a1 = 0.f;
        for (int d = 0; d < 128; ++d) {
            float xv = xsB[d];
            a0 = fmaf(xv, W1[d * 512 + tid], a0);
            a1 = fmaf(xv, W1[d * 512 + tid + 256], a1);
        }
        hb[tid]       = fmaxf(a0 + b1[e * 512 + tid], 0.f);
        hb[tid + 256] = fmaxf(a1 + b1[e * 512 + tid + 256], 0.f);
        __syncthreads();
        if (tid < 128) {
            const float* W2 = w2 + (size_t)e * (512 * 128);
            float a = 0.f;
            for (int h = 0; h < 512; ++h)
                a = fmaf(hb[h], W2[h * 128 + tid], a);
            oacc = fmaf(pw, a + b2[e * 128 + tid], oacc);
        }
        __syncthreads();
    }
    if (tid < 128)
        out[((size_t)b * 128 + tid) * NHW + hw] = oacc;
}

// ---------------- host launch ----------------
extern "C" void kernel_launch(void* const* d_in, const int* in_sizes, int n_in,
                              void* d_out, int out_size, void* d_ws, size_t ws_size,
                              hipStream_t stream) {
    const float* x       = (const float*)d_in[0];
    const float* gate_w  = (const float*)d_in[1];
    const float* gate_b  = (const float*)d_in[2];
    const float* noise_w = (const float*)d_in[3];
    const float* noise_b = (const float*)d_in[4];
    const float* w1      = (const float*)d_in[5];
    const float* b1      = (const float*)d_in[6];
    const float* w2      = (const float*)d_in[7];
    const float* b2      = (const float*)d_in[8];

    float* out   = (float*)d_out;                       // [32,128,32,32]
    float* gates = out + (size_t)NB * NC * NHW;         // [T,16]

    char* ws = (char*)d_ws;
    int*   top_idx  = (int*)ws;                          // T*2 ints   = 256 KiB
    float* top_prob = (float*)(ws + (size_t)NT * 2 * 4); // T*2 floats = 256 KiB
    float* xt_ws    = (float*)(ws + (size_t)NT * 4 * 4); // T*128 f32  = 16 MiB
    const size_t need_xt = (size_t)NT * 4 * 4 + (size_t)NT * 128 * 4;
    const int use_xt = (ws_size >= need_xt) ? 1 : 0;

    moe_gate_kernel<<<NT / 64, 256, 0, stream>>>(
        x, gate_w, gate_b, noise_w, noise_b,
        gates, top_idx, top_prob, xt_ws, use_xt);

    moe_expert_kernel<<<NT, 256, 0, stream>>>(
        x, xt_ws, use_xt, top_idx, top_prob, w1, b1, w2, b2, out);
}

// Round 2
// 304.222 us; speedup vs baseline: 7.1916x; 7.1916x over previous
//
#include <hip/hip_runtime.h>
#include <stdint.h>

// Problem constants (fixed by the reference)
#define NB       32
#define NC       128
#define NHW      1024            // H*W
#define NT       32768           // tokens
#define NE       16
#define NHID     512

typedef __attribute__((ext_vector_type(8))) short short8v;   // 8 x bf16 (4 VGPRs)
typedef __attribute__((ext_vector_type(4))) float f32x4;

__device__ __forceinline__ unsigned short f2bf(float f) {
    uint32_t u = __float_as_uint(f);
    uint32_t r = u + 0x7fffu + ((u >> 16) & 1u);   // RNE (finite values)
    return (unsigned short)(r >> 16);
}

// ---------------- Threefry-2x32, 20 rounds (JAX) ----------------
__device__ __forceinline__ uint32_t rotl32(uint32_t x, uint32_t d) {
    return (x << d) | (x >> (32u - d));
}

__device__ __forceinline__ void threefry2x32_20(uint32_t k0, uint32_t k1,
                                                uint32_t& x0, uint32_t& x1) {
    const uint32_t ks0 = k0, ks1 = k1, ks2 = k0 ^ k1 ^ 0x1BD11BDAu;
    x0 += ks0; x1 += ks1;
#define TFR(r) { x0 += x1; x1 = rotl32(x1, r); x1 ^= x0; }
    TFR(13u) TFR(15u) TFR(26u) TFR(6u)
    x0 += ks1; x1 += ks2 + 1u;
    TFR(17u) TFR(29u) TFR(16u) TFR(24u)
    x0 += ks2; x1 += ks0 + 2u;
    TFR(13u) TFR(15u) TFR(26u) TFR(6u)
    x0 += ks0; x1 += ks1 + 3u;
    TFR(17u) TFR(29u) TFR(16u) TFR(24u)
    x0 += ks1; x1 += ks2 + 4u;
    TFR(13u) TFR(15u) TFR(26u) TFR(6u)
    x0 += ks2; x1 += ks0 + 5u;
#undef TFR
}

__device__ __forceinline__ float erfinv_xla_f32(float x) {
    float w = -log1pf(-x * x);
    float p;
    if (w < 5.0f) {
        w = w - 2.5f;
        p = 2.81022636e-08f;
        p = fmaf(p, w, 3.43273939e-07f);
        p = fmaf(p, w, -3.5233877e-06f);
        p = fmaf(p, w, -4.39150654e-06f);
        p = fmaf(p, w, 0.00021858087f);
        p = fmaf(p, w, -0.00125372503f);
        p = fmaf(p, w, -0.00417768164f);
        p = fmaf(p, w, 0.246640727f);
        p = fmaf(p, w, 1.50140941f);
    } else {
        w = sqrtf(w) - 3.0f;
        p = -0.000200214257f;
        p = fmaf(p, w, 0.000100950558f);
        p = fmaf(p, w, 0.00134934322f);
        p = fmaf(p, w, -0.00367342844f);
        p = fmaf(p, w, 0.00573950773f);
        p = fmaf(p, w, -0.0076224613f);
        p = fmaf(p, w, 0.00943887047f);
        p = fmaf(p, w, 1.00167406f);
        p = fmaf(p, w, 2.83297682f);
    }
    return p * x;
}

__device__ __forceinline__ float jax_noise_elem(uint32_t i) {
    uint32_t x0 = 0u, x1 = i;
    threefry2x32_20(0u, 42u, x0, x1);
    uint32_t bits = x0 ^ x1;
    float f = __uint_as_float(0x3f800000u | (bits >> 9)) - 1.0f;
    const float lo = -0.99999994f;
    float u = f * 2.0f + lo;
    u = fmaxf(lo, u);
    return 1.41421354f * erfinv_xla_f32(u);
}

// ---------------- Kernel A: gating + noise + top-2 (+binning ranks, bf16 xt) ---
__global__ __launch_bounds__(256) void moe_gate_kernel(
    const float* __restrict__ x,
    const float* __restrict__ gate_w, const float* __restrict__ gate_b,
    const float* __restrict__ noise_w, const float* __restrict__ noise_b,
    float* __restrict__ gates_out,        // [T,16] region of d_out
    int*   __restrict__ top_idx,          // [T,2]
    float* __restrict__ top_prob,         // [T,2]
    int*   __restrict__ rank,             // [T,2]
    int*   __restrict__ cnt,              // [16]
    unsigned short* __restrict__ xtb,     // [T,128] bf16
    int do_new)
{
    __shared__ float xs[128][65];
    __shared__ float gw[128 * 16];
    __shared__ float nw[128 * 16];
    __shared__ float lg[64][17];

    const int tid = threadIdx.x;
    const int blk = blockIdx.x;
    const int b   = blk >> 4;
    const int hw0 = (blk & 15) << 6;
    const int t0  = blk * 64;

    {
        const size_t xbase = (size_t)b * (NC * NHW) + hw0;
        #pragma unroll
        for (int i = 0; i < 32; ++i) {
            int lin = i * 256 + tid;
            int c = lin >> 6, hwl = lin & 63;
            xs[c][hwl] = x[xbase + (size_t)c * NHW + hwl];
        }
    }
    #pragma unroll
    for (int i = 0; i < 8; ++i) {
        gw[i * 256 + tid] = gate_w[i * 256 + tid];
        nw[i * 256 + tid] = noise_w[i * 256 + tid];
    }
    __syncthreads();

    #pragma unroll
    for (int i = 0; i < 4; ++i) {
        int p = i * 256 + tid;
        int tok = p >> 4, e = p & 15;
        float ag = 0.f, an = 0.f;
        for (int d = 0; d < 128; ++d) {
            float xv = xs[d][tok];
            ag = fmaf(xv, gw[d * 16 + e], ag);
            an = fmaf(xv, nw[d * 16 + e], an);
        }
        ag += gate_b[e];
        an += noise_b[e];
        float sd = fmaxf(an, 0.f) + log1pf(expf(-fabsf(an)));
        uint32_t gi = (uint32_t)(t0 + tok) * 16u + (uint32_t)e;
        float nz = jax_noise_elem(gi);
        lg[tok][e] = fmaf(nz, sd, ag);
    }
    __syncthreads();

    if (tid < 64) {
        const int tok = tid;
        const int t = t0 + tok;
        float v1 = -INFINITY; int e1 = 0;
        #pragma unroll
        for (int e = 0; e < 16; ++e) {
            float v = lg[tok][e];
            if (v > v1) { v1 = v; e1 = e; }
        }
        float v2 = -INFINITY; int e2 = 0;
        #pragma unroll
        for (int e = 0; e < 16; ++e) {
            if (e == e1) continue;
            float v = lg[tok][e];
            if (v > v2) { v2 = v; e2 = e; }
        }
        float q = expf(v2 - v1);
        float s = 1.0f + q;
        float p1 = 1.0f / s;
        float p2 = q / s;
        #pragma unroll
        for (int e = 0; e < 16; ++e)
            gates_out[(size_t)t * 16 + e] = (e == e1) ? p1 : ((e == e2) ? p2 : 0.f);
        top_idx[t * 2 + 0] = e1;  top_idx[t * 2 + 1] = e2;
        top_prob[t * 2 + 0] = p1; top_prob[t * 2 + 1] = p2;
        if (do_new) {
            rank[t * 2 + 0] = atomicAdd(&cnt[e1], 1);
            rank[t * 2 + 1] = atomicAdd(&cnt[e2], 1);
        }
    }

    if (do_new) {
        #pragma unroll
        for (int i = 0; i < 32; ++i) {
            int lin = i * 256 + tid;
            int tok = lin >> 7, c = lin & 127;
            xtb[(size_t)(t0 + tok) * 128 + c] = f2bf(xs[c][tok]);
        }
    }
}

// ---------------- transpose + f32->bf16 convert: dst[c][r] = src[r][c] --------
__global__ __launch_bounds__(256) void transpose_convert_kernel(
    const float* __restrict__ src, unsigned short* __restrict__ dst, int R, int C)
{
    __shared__ float ts[64][65];
    const int nr = R >> 6, ncc = C >> 6;
    const int blk = blockIdx.x;
    const int e = blk / (nr * ncc);
    const int rem = blk % (nr * ncc);
    const int rt = rem / ncc, ct = rem % ncc;
    const float* S = src + (size_t)e * R * C + (size_t)(rt * 64) * C + ct * 64;
    unsigned short* D = dst + (size_t)e * R * C + (size_t)(ct * 64) * R + rt * 64;
    const int tid = threadIdx.x;
    #pragma unroll
    for (int i = 0; i < 16; ++i) {
        int lin = i * 256 + tid;
        int r = lin >> 6, c = lin & 63;
        ts[r][c] = S[(size_t)r * C + c];
    }
    __syncthreads();
    #pragma unroll
    for (int i = 0; i < 16; ++i) {
        int lin = i * 256 + tid;
        int c = lin >> 6, r = lin & 63;
        D[(size_t)c * R + r] = f2bf(ts[r][c]);
    }
}

// ---------------- scan: padded offsets, block->(e,chunk) table, pad fill ------
__global__ void scan_kernel(const int* __restrict__ cnt,
                            int* __restrict__ poff, int* __restrict__ blk2e,
                            int* __restrict__ blk2chunk, int* __restrict__ total_chunks,
                            int* __restrict__ pair_tok)
{
    __shared__ int spoff[16];
    __shared__ int snch[16];
    if (threadIdx.x == 0) {
        int off = 0, idx = 0;
        for (int e = 0; e < 16; ++e) {
            spoff[e] = off;
            int nch = (cnt[e] + 127) >> 7;
            snch[e] = nch;
            for (int c = 0; c < nch; ++c) { blk2e[idx] = e; blk2chunk[idx] = c; ++idx; }
            off += nch << 7;
        }
        *total_chunks = idx;
        for (int e = 0; e < 16; ++e) poff[e] = spoff[e];
    }
    __syncthreads();
    for (int e = 0; e < 16; ++e) {
        int start = spoff[e] + cnt[e];
        int end   = spoff[e] + (snch[e] << 7);
        for (int i = start + (int)threadIdx.x; i < end; i += (int)blockDim.x)
            pair_tok[i] = -1;
    }
}

// ---------------- scatter pairs into expert bins ------------------------------
__global__ __launch_bounds__(256) void scatter_kernel(
    const int* __restrict__ top_idx, const int* __restrict__ rank,
    const int* __restrict__ poff, int* __restrict__ pair_tok,
    int* __restrict__ slot_of)
{
    int i = blockIdx.x * 256 + threadIdx.x;   // 0..65535
    int t = i >> 1;
    int e = top_idx[i];
    int slot = poff[e] + rank[i];
    pair_tok[slot] = t;
    slot_of[i] = slot;
}

// ---------------- grouped MFMA MLP: 1 block = (expert, 128 pairs) -------------
__global__ __launch_bounds__(512, 1) void moe_mfma_kernel(
    const unsigned short* __restrict__ xtb,
    const int* __restrict__ pair_tok, const int* __restrict__ blk2e,
    const int* __restrict__ blk2chunk, const int* __restrict__ poff,
    const int* __restrict__ total_chunks,
    const unsigned short* __restrict__ w1bt,   // [E][HID][D] bf16
    const float* __restrict__ b1,
    const unsigned short* __restrict__ w2bt,   // [E][D][HID] bf16
    const float* __restrict__ b2,
    float* __restrict__ pair_y)                // [Ppad][128] f32
{
    __shared__ short Xs[128 * 136];
    __shared__ short Hs[128 * 136];
    __shared__ short W1t[128 * 136];   // rows: h_local, cols: d
    __shared__ short W2t[128 * 136];   // rows: d, cols: h_local
    __shared__ int   ptoks[128];

    const int blk = blockIdx.x;
    if (blk >= *total_chunks) return;
    const int e  = blk2e[blk];
    const int p0 = poff[e] + (blk2chunk[blk] << 7);
    const int tid  = threadIdx.x;
    const int lane = tid & 63;
    const int wid  = tid >> 6;       // 0..7
    const int wm   = wid >> 1;       // 0..3 -> m0 = wm*32
    const int wn   = wid & 1;        // 0..1 -> n0 = wn*64
    const int l16  = lane & 15;
    const int lg   = lane >> 4;      // 0..3

    if (tid < 128) ptoks[tid] = pair_tok[p0 + tid];
    __syncthreads();

    // stage X tile: 128 rows x 128 (bf16), 16B per thread-iter
    #pragma unroll
    for (int i = 0; i < 4; ++i) {
        int lin = i * 512 + tid;              // 0..2047
        int row = lin >> 4, kc = lin & 15;
        int tok = ptoks[row];
        short8v v = {};
        if (tok >= 0)
            v = *(const short8v*)(xtb + (size_t)tok * 128 + kc * 8);
        *(short8v*)(Xs + row * 136 + kc * 8) = v;
    }

    f32x4 yacc[2][4];
    #pragma unroll
    for (int mi = 0; mi < 2; ++mi)
        #pragma unroll
        for (int ni = 0; ni < 4; ++ni)
            yacc[mi][ni] = (f32x4){0.f, 0.f, 0.f, 0.f};

    const size_t w1base = (size_t)e * 512 * 128;
    const size_t w2base = (size_t)e * 128 * 512;

    for (int c = 0; c < 4; ++c) {
        const int hc = c << 7;
        // stage W1t chunk: rows h_local (global h = hc+row), cols d
        #pragma unroll
        for (int i = 0; i < 4; ++i) {
            int lin = i * 512 + tid;
            int row = lin >> 4, kc = lin & 15;
            short8v v = *(const short8v*)(w1bt + w1base + (size_t)(hc + row) * 128 + kc * 8);
            *(short8v*)(W1t + row * 136 + kc * 8) = v;
        }
        // stage W2t chunk: rows d, cols h_local (global h = hc+col)
        #pragma unroll
        for (int i = 0; i < 4; ++i) {
            int lin = i * 512 + tid;
            int row = lin >> 4, kc = lin & 15;
            short8v v = *(const short8v*)(w2bt + w2base + (size_t)row * 512 + hc + kc * 8);
            *(short8v*)(W2t + row * 136 + kc * 8) = v;
        }
        __syncthreads();

        // ---- layer 1: H = relu(X @ W1 + b1), this 128-wide hid chunk ----
        f32x4 hacc[2][4];
        #pragma unroll
        for (int mi = 0; mi < 2; ++mi)
            #pragma unroll
            for (int ni = 0; ni < 4; ++ni)
                hacc[mi][ni] = (f32x4){0.f, 0.f, 0.f, 0.f};

        #pragma unroll
        for (int kk = 0; kk < 4; ++kk) {
            short8v a0 = *(const short8v*)(Xs + (wm * 32 +      l16) * 136 + kk * 32 + lg * 8);
            short8v a1 = *(const short8v*)(Xs + (wm * 32 + 16 + l16) * 136 + kk * 32 + lg * 8);
            #pragma unroll
            for (int ni = 0; ni < 4; ++ni) {
                short8v bfr = *(const short8v*)(W1t + (wn * 64 + ni * 16 + l16) * 136 + kk * 32 + lg * 8);
                hacc[0][ni] = __builtin_amdgcn_mfma_f32_16x16x32_bf16(a0, bfr, hacc[0][ni], 0, 0, 0);
                hacc[1][ni] = __builtin_amdgcn_mfma_f32_16x16x32_bf16(a1, bfr, hacc[1][ni], 0, 0, 0);
            }
        }
        // relu + b1 -> Hs (bf16). D frag: col=lane&15, row=(lane>>4)*4+r
        #pragma unroll
        for (int ni = 0; ni < 4; ++ni) {
            float b1v = b1[e * 512 + hc + wn * 64 + ni * 16 + l16];
            #pragma unroll
            for (int mi = 0; mi < 2; ++mi) {
                #pragma unroll
                for (int r = 0; r < 4; ++r) {
                    float v = fmaxf(hacc[mi][ni][r] + b1v, 0.f);
                    Hs[(wm * 32 + mi * 16 + lg * 4 + r) * 136 + wn * 64 + ni * 16 + l16] =
                        (short)f2bf(v);
                }
            }
        }
        __syncthreads();

        // ---- layer 2: Y += H_chunk @ W2[hc:hc+128, :] ----
        #pragma unroll
        for (int kk = 0; kk < 4; ++kk) {
            short8v a0 = *(const short8v*)(Hs + (wm * 32 +      l16) * 136 + kk * 32 + lg * 8);
            short8v a1 = *(const short8v*)(Hs + (wm * 32 + 16 + l16) * 136 + kk * 32 + lg * 8);
            #pragma unroll
            for (int ni = 0; ni < 4; ++ni) {
                short8v bfr = *(const short8v*)(W2t + (wn * 64 + ni * 16 + l16) * 136 + kk * 32 + lg * 8);
                yacc[0][ni] = __builtin_amdgcn_mfma_f32_16x16x32_bf16(a0, bfr, yacc[0][ni], 0, 0, 0);
                yacc[1][ni] = __builtin_amdgcn_mfma_f32_16x16x32_bf16(a1, bfr, yacc[1][ni], 0, 0, 0);
            }
        }
        __syncthreads();   // before next chunk overwrites W1t/W2t/Hs
    }

    // epilogue: pair_y = Y + b2
    #pragma unroll
    for (int ni = 0; ni < 4; ++ni) {
        int d = wn * 64 + ni * 16 + l16;
        float b2v = b2[e * 128 + d];
        #pragma unroll
        for (int mi = 0; mi < 2; ++mi) {
            #pragma unroll
            for (int r = 0; r < 4; ++r) {
                int m = wm * 32 + mi * 16 + lg * 4 + r;
                pair_y[(size_t)(p0 + m) * 128 + d] = yacc[mi][ni][r] + b2v;
            }
        }
    }
}

// ---------------- combine: out[t] = p0*y0 + p1*y1 (NCHW store) ----------------
__global__ __launch_bounds__(256) void combine_kernel(
    const float* __restrict__ pair_y, const int* __restrict__ slot_of,
    const float* __restrict__ top_prob, float* __restrict__ out)
{
    __shared__ float ob[64][129];
    const int blk = blockIdx.x;               // 512
    const int b = blk >> 4;
    const int hw0 = (blk & 15) << 6;
    const int tid = threadIdx.x;
    #pragma unroll
    for (int i = 0; i < 32; ++i) {
        int lin = i * 256 + tid;
        int tl = lin >> 7, d = lin & 127;
        int t = b * 1024 + hw0 + tl;
        int s0 = slot_of[t * 2], s1 = slot_of[t * 2 + 1];
        float p0 = top_prob[t * 2], p1 = top_prob[t * 2 + 1];
        ob[tl][d] = p0 * pair_y[(size_t)s0 * 128 + d] + p1 * pair_y[(size_t)s1 * 128 + d];
    }
    __syncthreads();
    #pragma unroll
    for (int i = 0; i < 32; ++i) {
        int lin = i * 256 + tid;
        int d = lin >> 6, hwl = lin & 63;
        out[((size_t)b * 128 + d) * 1024 + hw0 + hwl] = ob[hwl][d];
    }
}

// ---------------- fallback (round-1) per-token expert kernel ------------------
__global__ __launch_bounds__(256) void moe_expert_kernel(
    const float* __restrict__ x,
    const int* __restrict__ top_idx, const float* __restrict__ top_prob,
    const float* __restrict__ w1, const float* __restrict__ b1,
    const float* __restrict__ w2, const float* __restrict__ b2,
    float* __restrict__ out)
{
    __shared__ float xsB[128];
    __shared__ float hb[512];

    const int tid = threadIdx.x;
    const int t = blockIdx.x;
    const int b = t >> 10, hw = t & 1023;

    if (tid < 128)
        xsB[tid] = x[((size_t)b * 128 + tid) * NHW + hw];
    __syncthreads();

    float oacc = 0.f;
    #pragma unroll
    for (int k = 0; k < 2; ++k) {
        const int e = top_idx[t * 2 + k];
        const float pw = top_prob[t * 2 + k];
        const float* W1 = w1 + (size_t)e * (128 * 512);
        float a0 = 0.f, a1 = 0.f;
        for (int d = 0; d < 128; ++d) {
            float xv = xsB[d];
            a0 = fmaf(xv, W1[d * 512 + tid], a0);
            a1 = fmaf(xv, W1[d * 512 + tid + 256], a1);
        }
        hb[tid]       = fmaxf(a0 + b1[e * 512 + tid], 0.f);
        hb[tid + 256] = fmaxf(a1 + b1[e * 512 + tid + 256], 0.f);
        __syncthreads();
        if (tid < 128) {
            const float* W2 = w2 + (size_t)e * (512 * 128);
            float a = 0.f;
            for (int h = 0; h < 512; ++h)
                a = fmaf(hb[h], W2[h * 128 + tid], a);
            oacc = fmaf(pw, a + b2[e * 128 + tid], oacc);
        }
        __syncthreads();
    }
    if (tid < 128)
        out[((size_t)b * 128 + tid) * NHW + hw] = oacc;
}

// ---------------- host launch -------------------------------------------------
extern "C" void kernel_launch(void* const* d_in, const int* in_sizes, int n_in,
                              void* d_out, int out_size, void* d_ws, size_t ws_size,
                              hipStream_t stream) {
    const float* x       = (const float*)d_in[0];
    const float* gate_w  = (const float*)d_in[1];
    const float* gate_b  = (const float*)d_in[2];
    const float* noise_w = (const float*)d_in[3];
    const float* noise_b = (const float*)d_in[4];
    const float* w1      = (const float*)d_in[5];
    const float* b1      = (const float*)d_in[6];
    const float* w2      = (const float*)d_in[7];
    const float* b2      = (const float*)d_in[8];

    float* out   = (float*)d_out;                   // [32,128,32,32]
    float* gates = out + (size_t)NB * NC * NHW;     // [T,16]

    // workspace layout (byte offsets)
    const size_t OFF_CNT    = 0;          // 16 ints
    const size_t OFF_POFF   = 1024;       // 16 ints
    const size_t OFF_TOTAL  = 2048;       // 1 int
    const size_t OFF_B2E    = 4096;       // 544 ints
    const size_t OFF_B2C    = 8192;       // 544 ints
    const size_t OFF_TIDX   = 12288;      // T*2 ints
    const size_t OFF_RANK   = OFF_TIDX + (size_t)NT * 2 * 4;       //  274432
    const size_t OFF_SLOT   = OFF_RANK + (size_t)NT * 2 * 4;       //  536576
    const size_t OFF_PROB   = OFF_SLOT + (size_t)NT * 2 * 4;       //  798720
    const size_t OFF_XTB    = OFF_PROB + (size_t)NT * 2 * 4;       // 1060864
    const size_t OFF_W1BT   = OFF_XTB + (size_t)NT * 128 * 2;      // +8 MiB
    const size_t OFF_W2BT   = OFF_W1BT + (size_t)NE * 512 * 128 * 2;
    const size_t OFF_PTOK   = OFF_W2BT + (size_t)NE * 128 * 512 * 2;
    const size_t NPAIR_PAD  = 67584;
    const size_t OFF_PAIRY  = OFF_PTOK + NPAIR_PAD * 4;
    const size_t NEED       = OFF_PAIRY + NPAIR_PAD * 128 * 4;

    char* ws = (char*)d_ws;
    int*   cnt      = (int*)(ws + OFF_CNT);
    int*   poff     = (int*)(ws + OFF_POFF);
    int*   total_ch = (int*)(ws + OFF_TOTAL);
    int*   blk2e    = (int*)(ws + OFF_B2E);
    int*   blk2c    = (int*)(ws + OFF_B2C);
    int*   top_idx  = (int*)(ws + OFF_TIDX);
    int*   rank     = (int*)(ws + OFF_RANK);
    int*   slot_of  = (int*)(ws + OFF_SLOT);
    float* top_prob = (float*)(ws + OFF_PROB);
    unsigned short* xtb  = (unsigned short*)(ws + OFF_XTB);
    unsigned short* w1bt = (unsigned short*)(ws + OFF_W1BT);
    unsigned short* w2bt = (unsigned short*)(ws + OFF_W2BT);
    int*   pair_tok = (int*)(ws + OFF_PTOK);
    float* pair_y   = (float*)(ws + OFF_PAIRY);

    const int use_new = (ws_size >= NEED) ? 1 : 0;

    if (use_new)
        hipMemsetAsync(cnt, 0, 16 * sizeof(int), stream);

    moe_gate_kernel<<<NT / 64, 256, 0, stream>>>(
        x, gate_w, gate_b, noise_w, noise_b,
        gates, top_idx, top_prob, rank, cnt, xtb, use_new);

    if (use_new) {
        // w1[e][128][512] -> w1bt[e][512][128] ; w2[e][512][128] -> w2bt[e][128][512]
        transpose_convert_kernel<<<NE * 2 * 8, 256, 0, stream>>>(w1, w1bt, 128, 512);
        transpose_convert_kernel<<<NE * 8 * 2, 256, 0, stream>>>(w2, w2bt, 512, 128);
        scan_kernel<<<1, 256, 0, stream>>>(cnt, poff, blk2e, blk2c, total_ch, pair_tok);
        scatter_kernel<<<NT * 2 / 256, 256, 0, stream>>>(top_idx, rank, poff, pair_tok, slot_of);
        moe_mfma_kernel<<<528, 512, 0, stream>>>(
            xtb, pair_tok, blk2e, blk2c, poff, total_ch,
            w1bt, b1, w2bt, b2, pair_y);
        combine_kernel<<<512, 256, 0, stream>>>(pair_y, slot_of, top_prob, out);
    } else {
        moe_expert_kernel<<<NT, 256, 0, stream>>>(
            x, top_idx, top_prob, w1, b1, w2, b2, out);
    }
}